// Round 1
// baseline (7385.733 us; speedup 1.0000x reference)
//
#include <hip/hip_runtime.h>

#define BB 32
#define TT 1000
#define HH 512
#define G4 2048
#define BTH ((size_t)BB * TT * HH)  // 16,384,000 elements per output tensor

typedef short short8 __attribute__((ext_vector_type(8)));
typedef float f32x4 __attribute__((ext_vector_type(4)));

__device__ __forceinline__ unsigned short f2bf(float f) {
    union { float f; unsigned u; } v; v.f = f;
    unsigned r = v.u + 0x7FFF + ((v.u >> 16) & 1);  // RNE; inputs finite
    return (unsigned short)(r >> 16);
}

__global__ void lstm_init_flags(int* flags) {
    // 256 flags, one per WG, spaced 32 ints (128B) apart
    flags[threadIdx.x * 32] = -1;
}

__global__ void __launch_bounds__(256, 1)
lstm_main(const float* __restrict__ wx, const float* __restrict__ u,
          const float* __restrict__ ub, const float* __restrict__ ht0,
          const float* __restrict__ ct0, float* __restrict__ out,
          unsigned short* __restrict__ ring, int* __restrict__ flags)
{
    // LDS: u-slice 64KB bf16 (swizzled), h 16KB bf16 (rows 0-3 valid, swizzled),
    // gates/acts 1KB each
    __shared__ __align__(16) unsigned short lds_u[64 * 512];
    __shared__ __align__(16) unsigned short lds_h[16 * 512];
    __shared__ float lds_gates[4 * 64];
    __shared__ float lds_acts[4 * 64];

    const int tid  = threadIdx.x;
    const int bid  = blockIdx.x;
    const int cg   = bid & 31;   // column group: owns h-cols [cg*16, cg*16+16)
    const int qb   = bid >> 5;   // batch group: owns batches [qb*4, qb*4+4)
    const int lane = tid & 63;
    const int wv   = tid >> 6;

    // ---- stage u slice (64 gate-rows x 512) as bf16 into LDS, XOR-swizzled ----
    for (int itr = 0; itr < 32; ++itr) {
        int r  = itr * 2 + (tid >> 7);        // 0..63
        int l1 = tid & 127;                   // 128 threads x float4 cover 512
        int gr = (r >> 4) * HH + cg * 16 + (r & 15);  // global u row
        const float4* src = (const float4*)(u + (size_t)gr * HH) + l1;
        float4 v = *src;
        int idx = (r * 512 + l1 * 4) ^ ((r & 7) << 3);  // ushort units; byte swz = (r&7)<<4
        union { ushort4 v4; unsigned short s[4]; } p;
        p.s[0] = f2bf(v.x); p.s[1] = f2bf(v.y); p.s[2] = f2bf(v.z); p.s[3] = f2bf(v.w);
        *(ushort4*)&lds_u[idx] = p.v4;
    }

    // zero pad rows 4..15 of lds_h (once)
    for (int j = 0; j < 3; ++j) {
        int idx8 = tid + j * 256;             // 768 x short8 = 12 rows x 512
        int r = 4 + (idx8 >> 6);
        int k = (idx8 & 63) * 8;
        int idx = (r * 512 + k) ^ ((r & 7) << 3);
        short8 z = {0, 0, 0, 0, 0, 0, 0, 0};
        *(short8*)&lds_h[idx] = z;
    }

    // stage initial h (from ht0, f32 -> bf16)
    {
        int r = tid >> 6;          // batch row 0..3
        int k = lane * 8;
        const float* src = ht0 + (size_t)(qb * 4 + r) * HH + k;
        float4 v0 = *(const float4*)src;
        float4 v1 = *(const float4*)(src + 4);
        union { short8 v8; unsigned short s[8]; } p;
        p.s[0] = f2bf(v0.x); p.s[1] = f2bf(v0.y); p.s[2] = f2bf(v0.z); p.s[3] = f2bf(v0.w);
        p.s[4] = f2bf(v1.x); p.s[5] = f2bf(v1.y); p.s[6] = f2bf(v1.z); p.s[7] = f2bf(v1.w);
        int idx = (r * 512 + k) ^ ((r & 7) << 3);
        *(short8*)&lds_h[idx] = p.v8;
    }

    // per-thread epilogue mapping: (batch bep, gate-col gc)
    const int gc   = tid & 63;
    const int bep  = tid >> 6;
    const int gate = gc >> 4;       // 0=i 1=f 2=g 3=o
    const int jc   = gc & 15;
    const float bias_r = ub[gate * HH + cg * 16 + jc];

    // persistent cell state: threads 0..63 own (b = tid>>4, j = tid&15)
    float c_reg = 0.f;
    if (tid < 64)
        c_reg = ct0[(size_t)(qb * 4 + (tid >> 4)) * HH + cg * 16 + (tid & 15)];

    // wx prefetch (2 steps ahead)
    const size_t wx0 = (size_t)(qb * 4 + bep) * TT * G4 + gate * HH + cg * 16 + jc;
    float wx_cur = wx[wx0];
    float wx_nxt = wx[wx0 + G4];

    // output bases
    const size_t ob_gate = (size_t)(2 + gate) * BTH +
                           (size_t)(qb * 4 + bep) * TT * HH + cg * 16 + jc;
    const size_t ob_hc = (size_t)(qb * 4 + (tid >> 4)) * TT * HH + cg * 16 + (tid & 15);

    // MFMA fragment addressing (A: row=lane&15 (batch), k=(lane>>4)*8+e;
    //                           B: col=lane&15 (gate-row), same k pattern)
    const int arow  = lane & 15;
    const int ahi   = lane >> 4;
    const int a_off = arow * 512 + ahi * 8;
    const int a_msk = (arow & 7) << 3;
    const int brow  = wv * 16 + arow;
    const int b_off = brow * 512 + ahi * 8;
    const int b_msk = (brow & 7) << 3;

    int* grp_flags = flags + qb * 32 * 32;

    __syncthreads();

    for (int t = 0; t < TT; ++t) {
        if (t > 0) {
            // every wave polls all 32 group flags (no barrier needed before loads)
            const int target = t - 1;
            for (;;) {
                int f = 0x7fffffff;
                if (lane < 32)
                    f = __hip_atomic_load(grp_flags + lane * 32,
                                          __ATOMIC_RELAXED, __HIP_MEMORY_SCOPE_AGENT);
                unsigned long long m = __ballot(f >= target);
                if ((m & 0xFFFFFFFFull) == 0xFFFFFFFFull) break;
            }
            // load group's h (4 batches x 512 bf16 = 4KB) from ring slot (t-1)&1
            const unsigned long long* rsrc =
                (const unsigned long long*)ring + ((size_t)((t - 1) & 1) * 8 + qb) * 512;
            unsigned long long q0 = __hip_atomic_load(rsrc + tid * 2,
                                        __ATOMIC_RELAXED, __HIP_MEMORY_SCOPE_AGENT);
            unsigned long long q1 = __hip_atomic_load(rsrc + tid * 2 + 1,
                                        __ATOMIC_RELAXED, __HIP_MEMORY_SCOPE_AGENT);
            int r = tid >> 6;
            int k = lane * 8;
            union { short8 v8; unsigned long long q[2]; } p;
            p.q[0] = q0; p.q[1] = q1;
            *(short8*)&lds_h[(r * 512 + k) ^ ((r & 7) << 3)] = p.v8;
            __syncthreads();   // h staged; also protects lds_h vs prev-step MFMA reads
        }

        const float wx_use = wx_cur;
        wx_cur = wx_nxt;
        if (t + 2 < TT) wx_nxt = wx[wx0 + (size_t)(t + 2) * G4];

        // ---- MFMA: wave wv computes gate-cols [wv*16, wv*16+16), K=512 ----
        f32x4 acc0 = {0.f, 0.f, 0.f, 0.f}, acc1 = {0.f, 0.f, 0.f, 0.f};
#pragma unroll
        for (int kk = 0; kk < 8; ++kk) {
            short8 a = *(const short8*)&lds_h[(a_off + kk * 32) ^ a_msk];
            short8 b = *(const short8*)&lds_u[(b_off + kk * 32) ^ b_msk];
            acc0 = __builtin_amdgcn_mfma_f32_16x16x32_bf16(a, b, acc0, 0, 0, 0);
        }
#pragma unroll
        for (int kk = 8; kk < 16; ++kk) {
            short8 a = *(const short8*)&lds_h[(a_off + kk * 32) ^ a_msk];
            short8 b = *(const short8*)&lds_u[(b_off + kk * 32) ^ b_msk];
            acc1 = __builtin_amdgcn_mfma_f32_16x16x32_bf16(a, b, acc1, 0, 0, 0);
        }
        f32x4 g = acc0 + acc1;
        // D layout: col = lane&15, row = (lane>>4)*4 + reg -> lanes 0-15 hold rows 0-3
        if (lane < 16) {
            int col = wv * 16 + lane;
#pragma unroll
            for (int rr = 0; rr < 4; ++rr) lds_gates[rr * 64 + col] = g[rr];
        }
        __syncthreads();

        // ---- epilogue: activations + gate outputs ----
        float gv = lds_gates[bep * 64 + gc] + wx_use + bias_r;
        float xs = (gate == 2) ? 2.f * gv : gv;
        float s  = 1.f / (1.f + __expf(-xs));
        float act = (gate == 2) ? 2.f * s - 1.f : s;  // tanh = 2*sigmoid(2x)-1
        out[ob_gate + (size_t)t * HH] = act;
        lds_acts[bep * 64 + gc] = act;
        __syncthreads();

        // ---- c/h update + publish (wave0 only) ----
        if (tid < 64) {
            int bbx = tid >> 4, j = tid & 15;
            float ai = lds_acts[bbx * 64 + j];
            float af = lds_acts[bbx * 64 + 16 + j];
            float ag = lds_acts[bbx * 64 + 32 + j];
            float ao = lds_acts[bbx * 64 + 48 + j];
            c_reg = af * c_reg + ai * ag;
            float e2 = __expf(-2.f * c_reg);
            float th = 2.f / (1.f + e2) - 1.f;
            float hn = ao * th;
            out[ob_hc + (size_t)t * HH] = hn;
            out[BTH + ob_hc + (size_t)t * HH] = c_reg;
            // publish h-slice as bf16 (pack pairs -> u32, device-scope stores)
            unsigned hb = (unsigned)f2bf(hn);
            unsigned nb = (unsigned)__shfl_down((int)hb, 1);
            if ((j & 1) == 0) {
                unsigned pk = hb | (nb << 16);
                unsigned* rdst = (unsigned*)ring + ((size_t)(t & 1) * 8 + qb) * 1024 +
                                 ((unsigned)(bbx * 512 + cg * 16 + j) >> 1);
                __hip_atomic_store(rdst, pk, __ATOMIC_RELAXED, __HIP_MEMORY_SCOPE_AGENT);
            }
        }
        // flag release: wave0 program order guarantees ring stores precede this;
        // RELEASE drains vmcnt + writes back before flag becomes visible
        if (tid == 0)
            __hip_atomic_store(flags + (qb * 32 + cg) * 32, t,
                               __ATOMIC_RELEASE, __HIP_MEMORY_SCOPE_AGENT);
    }
}

extern "C" void kernel_launch(void* const* d_in, const int* in_sizes, int n_in,
                              void* d_out, int out_size, void* d_ws, size_t ws_size,
                              hipStream_t stream) {
    const float* wx = (const float*)d_in[0];
    const float* u  = (const float*)d_in[1];
    const float* ub = (const float*)d_in[2];
    const float* ht = (const float*)d_in[3];
    const float* ct = (const float*)d_in[4];
    float* out = (float*)d_out;
    unsigned short* ring = (unsigned short*)d_ws;          // 2*8*2048 bf16 = 64KB
    int* flags = (int*)((char*)d_ws + 65536);              // 256 flags, 128B spaced

    lstm_init_flags<<<1, 256, 0, stream>>>(flags);

    void* args[] = {(void*)&wx, (void*)&u, (void*)&ub, (void*)&ht,
                    (void*)&ct, (void*)&out, (void*)&ring, (void*)&flags};
    hipLaunchCooperativeKernel((void*)lstm_main, dim3(256), dim3(256), args, 0, stream);
}

// Round 2
// 1702.068 us; speedup vs baseline: 4.3393x; 4.3393x over previous
//
#include <hip/hip_runtime.h>

#define BB 32
#define TT 1000
#define HH 512
#define G4 2048
#define BTH ((size_t)BB * TT * HH)  // elements per output tensor

typedef short short8 __attribute__((ext_vector_type(8)));
typedef float f32x4 __attribute__((ext_vector_type(4)));

__device__ __forceinline__ unsigned short f2bf(float f) {
    union { float f; unsigned u; } v; v.f = f;
    unsigned r = v.u + 0x7FFF + ((v.u >> 16) & 1);  // RNE; inputs finite
    return (unsigned short)(r >> 16);
}

// ring: u32 words [2 slots][8 groups][32 producers x 64 words]
// word = (bf16(h) << 16) | (t & 0xFFFF)  -- self-tagged, no fences needed
#define RING_WORDS (2 * 8 * 32 * 64)

__global__ void lstm_init_ring(unsigned* ring) {
    int i = blockIdx.x * 256 + threadIdx.x;
    // tag 0xFFFF matches no step t<1000; agent-scope so zero L2-residency issues
    __hip_atomic_store(ring + i, 0xFFFFFFFFu, __ATOMIC_RELAXED,
                       __HIP_MEMORY_SCOPE_AGENT);
}

__global__ void __launch_bounds__(256, 1)
lstm_main(const float* __restrict__ wx, const float* __restrict__ u,
          const float* __restrict__ ub, const float* __restrict__ ht0,
          const float* __restrict__ ct0, float* __restrict__ out,
          unsigned* __restrict__ ring)
{
    __shared__ __align__(16) unsigned short lds_h[16 * 512];  // 16KB, XOR-swizzled
    __shared__ float lds_gates[4 * 64];                       // [b][gate*16+j]

    const int tid  = threadIdx.x;
    const int bid  = blockIdx.x;
    const int cg   = bid & 31;   // owns h/gate cols [cg*16, cg*16+16)
    const int qb   = bid >> 5;   // owns batches [qb*4, qb*4+4)
    const int lane = tid & 63;
    const int wv   = tid >> 6;   // wave index; doubles as batch row in epilogue

    // ---- zero pad rows 4..15 of lds_h (once) ----
    for (int j = 0; j < 3; ++j) {
        int idx8 = tid + j * 256;             // 768 x short8 = 12 rows x 512
        int r = 4 + (idx8 >> 6);
        int k = (idx8 & 63) * 8;
        short8 z = {0, 0, 0, 0, 0, 0, 0, 0};
        *(short8*)&lds_h[(r * 512 + k) ^ ((r & 7) << 3)] = z;
    }
    // ---- stage initial h (f32 -> bf16) ----
    {
        int r = wv;                           // batch row 0..3
        int k = lane * 8;
        const float* src = ht0 + (size_t)(qb * 4 + r) * HH + k;
        float4 v0 = *(const float4*)src;
        float4 v1 = *(const float4*)(src + 4);
        union { short8 v8; unsigned short s[8]; } p;
        p.s[0] = f2bf(v0.x); p.s[1] = f2bf(v0.y); p.s[2] = f2bf(v0.z); p.s[3] = f2bf(v0.w);
        p.s[4] = f2bf(v1.x); p.s[5] = f2bf(v1.y); p.s[6] = f2bf(v1.z); p.s[7] = f2bf(v1.w);
        *(short8*)&lds_h[(r * 512 + k) ^ ((r & 7) << 3)] = p.v8;
    }

    // ---- preload u fragments into registers (u is loop-invariant) ----
    // B-frag: N-col = wv*16 + (lane&15) -> global u row wv*512 + cg*16 + arow;
    // k = (lane>>4)*8 + e + kk*32  (same pattern as the passing R1 kernel's LDS read)
    const int arow = lane & 15, ahi = lane >> 4;
    short8 breg[16];
    {
        const float* bp = u + (size_t)(wv * HH + cg * 16 + arow) * HH + ahi * 8;
#pragma unroll
        for (int kk = 0; kk < 16; ++kk) {
            float4 v0 = *(const float4*)(bp + kk * 32);
            float4 v1 = *(const float4*)(bp + kk * 32 + 4);
            union { short8 v8; unsigned short s[8]; } p;
            p.s[0] = f2bf(v0.x); p.s[1] = f2bf(v0.y); p.s[2] = f2bf(v0.z); p.s[3] = f2bf(v0.w);
            p.s[4] = f2bf(v1.x); p.s[5] = f2bf(v1.y); p.s[6] = f2bf(v1.z); p.s[7] = f2bf(v1.w);
            breg[kk] = p.v8;
        }
    }

    // ---- per-thread epilogue mapping: (batch b = wv, gate-col gc = lane) ----
    const int gate = lane >> 4;
    const int jc   = lane & 15;
    const float bias_r = ub[gate * HH + cg * 16 + jc];

    // c-state: wave wv lanes 0..15 own (b = wv, j = lane)
    float c_reg = 0.f;
    if (lane < 16)
        c_reg = ct0[(size_t)(qb * 4 + wv) * HH + cg * 16 + lane];

    // wx prefetch (2 steps ahead)
    const size_t wx0 = (size_t)(qb * 4 + wv) * TT * G4 + gate * HH + cg * 16 + jc;
    float wx_cur = wx[wx0];
    float wx_nxt = wx[wx0 + G4];

    const size_t ob_gate = (size_t)(2 + gate) * BTH +
                           (size_t)(qb * 4 + wv) * TT * HH + cg * 16 + jc;
    const size_t ob_h = (size_t)(qb * 4 + wv) * TT * HH + cg * 16 + lane; // lanes<16

    // A-frag addressing (row = lane&15 = batch, k = (lane>>4)*8 + e + kk*32)
    const int a_off = arow * 512 + ahi * 8;
    const int a_msk = (arow & 7) << 3;

    // consumer mapping: thread handles 8 consecutive ring words of one producer
    const int myp = tid >> 3;            // producer 0..31
    const int mw  = (tid & 7) * 8;       // word offset 0..56
    const int mb  = mw >> 4;             // batch row of those 8 words
    const int mj  = mw & 15;             // 0 or 8

    __syncthreads();

    for (int t = 0; t < TT; ++t) {
        // ---- phase 1: acquire h_{t-1} from other 31 producers ----
        if (t > 0 && myp != cg) {
            const unsigned long long* src = (const unsigned long long*)
                (ring + ((size_t)((t - 1) & 1) * 8 + qb) * 2048 + myp * 64 + mw);
            const unsigned tg = (unsigned)((t - 1) & 0xFFFF);
            const unsigned long long want =
                (unsigned long long)tg | ((unsigned long long)tg << 32);
            const unsigned long long msk = 0x0000FFFF0000FFFFull;
            unsigned long long q0, q1, q2, q3;
            for (;;) {
                q0 = __hip_atomic_load(src + 0, __ATOMIC_RELAXED, __HIP_MEMORY_SCOPE_AGENT);
                q1 = __hip_atomic_load(src + 1, __ATOMIC_RELAXED, __HIP_MEMORY_SCOPE_AGENT);
                q2 = __hip_atomic_load(src + 2, __ATOMIC_RELAXED, __HIP_MEMORY_SCOPE_AGENT);
                q3 = __hip_atomic_load(src + 3, __ATOMIC_RELAXED, __HIP_MEMORY_SCOPE_AGENT);
                if (((q0 & msk) == want) & ((q1 & msk) == want) &
                    ((q2 & msk) == want) & ((q3 & msk) == want)) break;
            }
            union { short8 v8; unsigned u[4]; } pv;
            pv.u[0] = ((unsigned)(q0 >> 16) & 0xFFFFu) | ((unsigned)(q0 >> 48) << 16);
            pv.u[1] = ((unsigned)(q1 >> 16) & 0xFFFFu) | ((unsigned)(q1 >> 48) << 16);
            pv.u[2] = ((unsigned)(q2 >> 16) & 0xFFFFu) | ((unsigned)(q2 >> 48) << 16);
            pv.u[3] = ((unsigned)(q3 >> 16) & 0xFFFFu) | ((unsigned)(q3 >> 48) << 16);
            *(short8*)&lds_h[(mb * 512 + myp * 16 + mj) ^ ((mb & 7) << 3)] = pv.v8;
        }
        __syncthreads();   // S1: h staged; also orders gate-writes vs prior epilogue reads

        const float wx_use = wx_cur;
        wx_cur = wx_nxt;
        if (t + 2 < TT) wx_nxt = wx[wx0 + (size_t)(t + 2) * G4];

        // ---- phase 2: MFMA, wave wv computes gate-cols [wv*16, wv*16+16), K=512 ----
        f32x4 acc0 = {0.f, 0.f, 0.f, 0.f}, acc1 = {0.f, 0.f, 0.f, 0.f};
#pragma unroll
        for (int kk = 0; kk < 8; ++kk) {
            short8 a0 = *(const short8*)&lds_h[(a_off + kk * 32) ^ a_msk];
            short8 a1 = *(const short8*)&lds_h[(a_off + (kk + 8) * 32) ^ a_msk];
            acc0 = __builtin_amdgcn_mfma_f32_16x16x32_bf16(a0, breg[kk], acc0, 0, 0, 0);
            acc1 = __builtin_amdgcn_mfma_f32_16x16x32_bf16(a1, breg[kk + 8], acc1, 0, 0, 0);
        }
        f32x4 g = acc0 + acc1;
        // D: col = lane&15, row = (lane>>4)*4 + reg -> lanes 0-15 hold batch rows 0-3
        if (lane < 16) {
#pragma unroll
            for (int rr = 0; rr < 4; ++rr)
                lds_gates[rr * 64 + wv * 16 + lane] = g[rr];
        }
        __syncthreads();   // S2: gates visible

        // ---- phase 3: activations, c/h update, publish (no more barriers) ----
        float gv = lds_gates[wv * 64 + lane] + wx_use + bias_r;
        float xs = (gate == 2) ? 2.f * gv : gv;
        float s  = 1.f / (1.f + __expf(-xs));
        float act = (gate == 2) ? 2.f * s - 1.f : s;  // tanh = 2*sigmoid(2x)-1

        // gather the 4 gate acts for (b=wv, j): lanes j, j+16, j+32, j+48
        float af = __shfl(act, (lane & 15) + 16, 64);
        float ag = __shfl(act, (lane & 15) + 32, 64);
        float ao = __shfl(act, (lane & 15) + 48, 64);
        if (lane < 16) {
            c_reg = af * c_reg + act * ag;   // act == i-gate for lanes<16
            float e2 = __expf(-2.f * c_reg);
            float th = 2.f / (1.f + e2) - 1.f;
            float hn = ao * th;
            unsigned short hb = f2bf(hn);
            // publish FIRST (fire-and-forget, self-tagged)
            unsigned pk = ((unsigned)hb << 16) | (unsigned)(t & 0xFFFF);
            __hip_atomic_store(ring + ((size_t)(t & 1) * 8 + qb) * 2048 +
                                   cg * 64 + wv * 16 + lane,
                               pk, __ATOMIC_RELAXED, __HIP_MEMORY_SCOPE_AGENT);
            // own-column stage for next step (consumers skip myp==cg)
            lds_h[(wv * 512 + cg * 16 + lane) ^ ((wv & 7) << 3)] = hb;
            // output stores last — nothing ever waits on them
            out[ob_h + (size_t)t * HH] = hn;
            out[BTH + ob_h + (size_t)t * HH] = c_reg;
        }
        out[ob_gate + (size_t)t * HH] = act;
    }
}

extern "C" void kernel_launch(void* const* d_in, const int* in_sizes, int n_in,
                              void* d_out, int out_size, void* d_ws, size_t ws_size,
                              hipStream_t stream) {
    const float* wx = (const float*)d_in[0];
    const float* u  = (const float*)d_in[1];
    const float* ub = (const float*)d_in[2];
    const float* ht = (const float*)d_in[3];
    const float* ct = (const float*)d_in[4];
    float* out = (float*)d_out;
    unsigned* ring = (unsigned*)d_ws;   // RING_WORDS u32 = 128KB

    lstm_init_ring<<<RING_WORDS / 256, 256, 0, stream>>>(ring);

    void* args[] = {(void*)&wx, (void*)&u, (void*)&ub, (void*)&ht,
                    (void*)&ct, (void*)&out, (void*)&ring};
    hipLaunchCooperativeKernel((void*)lstm_main, dim3(256), dim3(256), args, 0, stream);
}